// Round 1
// baseline (59.795 us; speedup 1.0000x reference)
//
#include <hip/hip_runtime.h>
#include <hip/hip_bf16.h>

// JaccardLoss: per-(B,C) slice IoU of the ==1 masks, mean over slices, ×100.
// B=32, C=1, H=W=1024. Inputs fp32 containing exactly 0.0 or 1.0.
// Memory-bound: 268 MB read -> ~43us HBM roofline.

#define SLICES 32
#define SLICE_ELEMS (1024 * 1024)          // per-slice element count
#define SLICE_F4 (SLICE_ELEMS / 4)         // 262144 float4 per slice
#define BLOCKS_PER_SLICE 64
#define CHUNK_F4 (SLICE_F4 / BLOCKS_PER_SLICE)  // 4096 float4 per block
#define THREADS 256

__global__ __launch_bounds__(THREADS) void jaccard_count_kernel(
    const float4* __restrict__ out, const float4* __restrict__ tgt,
    int* __restrict__ counters /* [SLICES][2] = {inter, union} */) {
    const int slice = blockIdx.x / BLOCKS_PER_SLICE;
    const int sub   = blockIdx.x % BLOCKS_PER_SLICE;
    const size_t base = (size_t)slice * SLICE_F4 + (size_t)sub * CHUNK_F4;

    int inter = 0, uni = 0;
    for (int i = threadIdx.x; i < CHUNK_F4; i += THREADS) {
        float4 a = out[base + i];
        float4 b = tgt[base + i];
        bool a0 = (a.x == 1.0f), a1 = (a.y == 1.0f), a2 = (a.z == 1.0f), a3 = (a.w == 1.0f);
        bool b0 = (b.x == 1.0f), b1 = (b.y == 1.0f), b2 = (b.z == 1.0f), b3 = (b.w == 1.0f);
        inter += (int)(a0 && b0) + (int)(a1 && b1) + (int)(a2 && b2) + (int)(a3 && b3);
        uni   += (int)(a0 || b0) + (int)(a1 || b1) + (int)(a2 || b2) + (int)(a3 || b3);
    }

    // wave-64 reduce
    for (int off = 32; off > 0; off >>= 1) {
        inter += __shfl_down(inter, off);
        uni   += __shfl_down(uni, off);
    }

    __shared__ int sI[THREADS / 64], sU[THREADS / 64];
    const int wid  = threadIdx.x >> 6;
    const int lane = threadIdx.x & 63;
    if (lane == 0) { sI[wid] = inter; sU[wid] = uni; }
    __syncthreads();
    if (threadIdx.x == 0) {
        int I = 0, U = 0;
        #pragma unroll
        for (int w = 0; w < THREADS / 64; ++w) { I += sI[w]; U += sU[w]; }
        atomicAdd(&counters[slice * 2 + 0], I);
        atomicAdd(&counters[slice * 2 + 1], U);
    }
}

__global__ void jaccard_finalize_kernel(const int* __restrict__ counters,
                                        float* __restrict__ out) {
    const int lane = threadIdx.x;  // 64 threads, 1 block
    float iou = 0.0f;
    if (lane < SLICES) {
        float I = (float)counters[lane * 2 + 0];
        float U = (float)counters[lane * 2 + 1];
        iou = I / (U + 1e-7f);
    }
    for (int off = 32; off > 0; off >>= 1) iou += __shfl_down(iou, off);
    if (lane == 0) out[0] = iou * (100.0f / (float)SLICES);
}

extern "C" void kernel_launch(void* const* d_in, const int* in_sizes, int n_in,
                              void* d_out, int out_size, void* d_ws, size_t ws_size,
                              hipStream_t stream) {
    const float4* out_p = (const float4*)d_in[0];
    const float4* tgt_p = (const float4*)d_in[1];
    int* counters = (int*)d_ws;
    float* res = (float*)d_out;

    // zero the 64 counters every call (harness does not re-poison between replays)
    hipMemsetAsync(counters, 0, SLICES * 2 * sizeof(int), stream);

    jaccard_count_kernel<<<SLICES * BLOCKS_PER_SLICE, THREADS, 0, stream>>>(
        out_p, tgt_p, counters);
    jaccard_finalize_kernel<<<1, 64, 0, stream>>>(counters, res);
}